// Round 2
// baseline (354.685 us; speedup 1.0000x reference)
//
#include <hip/hip_runtime.h>
#include <hip/hip_bf16.h>

// Problem constants (B,S,E,H,D) = (4,2048,1024,16,64)
#define PB 4
#define PS 2048
#define PE 1024
#define PH 16
#define PD 64

typedef __attribute__((ext_vector_type(8))) short bf16x8;
typedef __attribute__((ext_vector_type(4))) float f32x4;
typedef const __attribute__((address_space(1))) unsigned int* gas_t;
typedef __attribute__((address_space(3))) unsigned int* las_t;

__device__ __forceinline__ unsigned short f2bf(float f) {
  union { float f; unsigned int u; } v;
  v.f = f;
  unsigned int u = v.u;
  u += 0x7fffu + ((u >> 16) & 1u);  // RNE
  return (unsigned short)(u >> 16);
}

__device__ __forceinline__ f32x4 mfma16(bf16x8 a, bf16x8 b, f32x4 c) {
  return __builtin_amdgcn_mfma_f32_16x16x32_bf16(a, b, c, 0, 0, 0);
}

// ---------------- fp32 -> bf16 conversion (x, Wk, Wq, Wo fused) --------------
#define CVT_GROUPS ((PB * PS * PE + 3 * PE * PE) / 4)
#define CVT_BLOCKS (CVT_GROUPS / 256)   // 11264
__global__ __launch_bounds__(256) void cvt_kernel(
    const float* __restrict__ x, const float* __restrict__ wk,
    const float* __restrict__ wq, const float* __restrict__ wo,
    unsigned short* __restrict__ xb, unsigned short* __restrict__ wkb,
    unsigned short* __restrict__ wqb, unsigned short* __restrict__ wob) {
  const long long NX = (long long)PB * PS * PE;   // 8388608
  const long long NW = (long long)PE * PE;        // 1048576
  long long i = ((long long)blockIdx.x * 256 + threadIdx.x) * 4;
  const float* src;
  unsigned short* dst;
  long long off;
  if (i < NX)               { src = x;  dst = xb;  off = i; }
  else if (i < NX + NW)     { src = wk; dst = wkb; off = i - NX; }
  else if (i < NX + 2 * NW) { src = wq; dst = wqb; off = i - NX - NW; }
  else                      { src = wo; dst = wob; off = i - NX - 2 * NW; }
  float4 v = *(const float4*)(src + off);
  ushort4 o;
  o.x = f2bf(v.x); o.y = f2bf(v.y); o.z = f2bf(v.z); o.w = f2bf(v.w);
  *(ushort4*)(dst + off) = o;
}

// ---------------- fused Q+K NT GEMM --------------------------------------
// {Q,K}[M,N] = x[M,K] * {Wq,Wk}[N,K]^T. 128x128 tile, BK=64, A-tile staged
// ONCE for both outputs. LDS layout [row][8 chunks of 8 elem] with
// GLOBAL-side XOR chunk swizzle; DMA dest stays lane-contiguous.
// Q written TRANSPOSED per-head (QT[((b*PH+h)*PD+d)*PS+s]); K row-major,
// PRE-SCALED by log2(e)/32 so attn's exp2 needs no per-score multiply
// (Q cannot be scaled: QT doubles as V via the reference's V=Q bug).
__global__ __launch_bounds__(256) void gemm_qk(
    const unsigned short* __restrict__ A, const unsigned short* __restrict__ Bq,
    const unsigned short* __restrict__ Bk,
    unsigned short* __restrict__ QT, unsigned short* __restrict__ Kb) {
  const int K = PE, N = PE;
  __shared__ __attribute__((aligned(16))) unsigned short As[128 * 64];
  __shared__ __attribute__((aligned(16))) unsigned short Bqs[128 * 64];
  __shared__ __attribute__((aligned(16))) unsigned short Bks[128 * 64];
  const int tid = threadIdx.x;
  const int wave = tid >> 6, lane = tid & 63;
  const int quad = lane >> 4, ln = lane & 15;
  const int m0 = blockIdx.y * 128, n0 = blockIdx.x * 128;
  const int wm = (wave >> 1) * 64, wn = (wave & 1) * 64;

  f32x4 aq[4][4], ak[4][4];
#pragma unroll
  for (int i = 0; i < 4; ++i)
#pragma unroll
    for (int j = 0; j < 4; ++j)
#pragma unroll
      for (int r = 0; r < 4; ++r) { aq[i][j][r] = 0.f; ak[i][j][r] = 0.f; }

  for (int k0 = 0; k0 < K; k0 += 64) {
#pragma unroll
    for (int it = 0; it < 4; ++it) {
      const int idx = it * 256 + tid;
      const int row = idx >> 3, ch = idx & 7;
      const int gch = ch ^ (row & 7);
      __builtin_amdgcn_global_load_lds(
          (gas_t)(const void*)(A + (size_t)(m0 + row) * K + k0 + gch * 8),
          (las_t)(void*)((char*)As + idx * 16), 16, 0, 0);
      __builtin_amdgcn_global_load_lds(
          (gas_t)(const void*)(Bq + (size_t)(n0 + row) * K + k0 + gch * 8),
          (las_t)(void*)((char*)Bqs + idx * 16), 16, 0, 0);
      __builtin_amdgcn_global_load_lds(
          (gas_t)(const void*)(Bk + (size_t)(n0 + row) * K + k0 + gch * 8),
          (las_t)(void*)((char*)Bks + idx * 16), 16, 0, 0);
    }
    __syncthreads();
#pragma unroll
    for (int kc = 0; kc < 2; ++kc) {
      bf16x8 af[4], bqf[4], bkf[4];
#pragma unroll
      for (int t = 0; t < 4; ++t) {
        const int ra = wm + t * 16 + ln;
        const int rb = wn + t * 16 + ln;
        af[t]  = *(const bf16x8*)(As  + ra * 64 + ((kc * 4 + quad) ^ (ra & 7)) * 8);
        bqf[t] = *(const bf16x8*)(Bqs + rb * 64 + ((kc * 4 + quad) ^ (rb & 7)) * 8);
        bkf[t] = *(const bf16x8*)(Bks + rb * 64 + ((kc * 4 + quad) ^ (rb & 7)) * 8);
      }
#pragma unroll
      for (int mt = 0; mt < 4; ++mt)
#pragma unroll
        for (int nt = 0; nt < 4; ++nt) {
          aq[mt][nt] = mfma16(af[mt], bqf[nt], aq[mt][nt]);
          ak[mt][nt] = mfma16(af[mt], bkf[nt], ak[mt][nt]);
        }
    }
    __syncthreads();
  }

  const float CEXP = 0.045084220f;  // log2(e)/32 folded into K
#pragma unroll
  for (int mt = 0; mt < 4; ++mt) {
#pragma unroll
    for (int nt = 0; nt < 4; ++nt) {
      const int row = m0 + wm + mt * 16 + quad * 4;  // +r
      const int col = n0 + wn + nt * 16 + ln;
      // Q: transposed per-head store (4 consecutive tokens -> one 8B store)
      const int b = row >> 11, s = row & 2047;
      const int h = col >> 6, d = col & 63;
      ushort4 ov;
      ov.x = f2bf(aq[mt][nt][0]); ov.y = f2bf(aq[mt][nt][1]);
      ov.z = f2bf(aq[mt][nt][2]); ov.w = f2bf(aq[mt][nt][3]);
      *(ushort4*)(QT + (((size_t)(b * PH + h) * PD + d) * PS + s)) = ov;
      // K: row-major, pre-scaled
#pragma unroll
      for (int r = 0; r < 4; ++r)
        Kb[(size_t)(row + r) * N + col] = f2bf(ak[mt][nt][r] * CEXP);
    }
  }
}

// ---------------- out-projection NT GEMM: C = A * Wo^T + bo (fp32) ----------
__global__ __launch_bounds__(256) void gemm_out(
    const unsigned short* __restrict__ A, const unsigned short* __restrict__ Bm,
    const float* __restrict__ bias, float* __restrict__ Cf) {
  const int K = PE, N = PE;
  __shared__ __attribute__((aligned(16))) unsigned short As[128 * 64];
  __shared__ __attribute__((aligned(16))) unsigned short Bs[128 * 64];
  const int tid = threadIdx.x;
  const int wave = tid >> 6, lane = tid & 63;
  const int quad = lane >> 4, ln = lane & 15;
  const int m0 = blockIdx.y * 128, n0 = blockIdx.x * 128;
  const int wm = (wave >> 1) * 64, wn = (wave & 1) * 64;

  f32x4 acc[4][4];
#pragma unroll
  for (int i = 0; i < 4; ++i)
#pragma unroll
    for (int j = 0; j < 4; ++j)
#pragma unroll
      for (int r = 0; r < 4; ++r) acc[i][j][r] = 0.f;

  for (int k0 = 0; k0 < K; k0 += 64) {
#pragma unroll
    for (int it = 0; it < 4; ++it) {
      const int idx = it * 256 + tid;
      const int row = idx >> 3, ch = idx & 7;
      const int gch = ch ^ (row & 7);
      __builtin_amdgcn_global_load_lds(
          (gas_t)(const void*)(A + (size_t)(m0 + row) * K + k0 + gch * 8),
          (las_t)(void*)((char*)As + idx * 16), 16, 0, 0);
      __builtin_amdgcn_global_load_lds(
          (gas_t)(const void*)(Bm + (size_t)(n0 + row) * K + k0 + gch * 8),
          (las_t)(void*)((char*)Bs + idx * 16), 16, 0, 0);
    }
    __syncthreads();
#pragma unroll
    for (int kc = 0; kc < 2; ++kc) {
      bf16x8 af[4], bfr[4];
#pragma unroll
      for (int t = 0; t < 4; ++t) {
        const int ra = wm + t * 16 + ln;
        const int rb = wn + t * 16 + ln;
        af[t]  = *(const bf16x8*)(As + ra * 64 + ((kc * 4 + quad) ^ (ra & 7)) * 8);
        bfr[t] = *(const bf16x8*)(Bs + rb * 64 + ((kc * 4 + quad) ^ (rb & 7)) * 8);
      }
#pragma unroll
      for (int mt = 0; mt < 4; ++mt)
#pragma unroll
        for (int nt = 0; nt < 4; ++nt)
          acc[mt][nt] = mfma16(af[mt], bfr[nt], acc[mt][nt]);
    }
    __syncthreads();
  }

#pragma unroll
  for (int mt = 0; mt < 4; ++mt) {
#pragma unroll
    for (int nt = 0; nt < 4; ++nt) {
      const int row = m0 + wm + mt * 16 + quad * 4;
      const int col = n0 + wn + nt * 16 + ln;
      const float bv = bias[col];
#pragma unroll
      for (int r = 0; r < 4; ++r)
        Cf[(size_t)(row + r) * N + col] = acc[mt][nt][r] + bv;
    }
  }
}

// ---------------- fused causal attention, V == Q (reference bug) -------------
// v3: 2-phase software pipeline (T3-minimum).
//  * K staged via global_load_lds into DOUBLE-BUFFERED Ks[2] — tile t+1's
//    DMA is issued BEFORE computing tile t, so the (single) barrier per
//    tile no longer exposes load latency (previous structure drained
//    vmcnt(0) immediately after issue: ~17% MfmaUtil).
//  * V (== Q) fragments read DIRECTLY from global QT (16B contiguous per
//    lane; 8KB tile, L1-cached across the 4 waves) — no Vs staging, no
//    second DMA stream. Issued at loop top to land under QK^T+softmax.
//  * s_setprio(1) around both MFMA clusters (T5).
// LDS: 2*8KB Ks + 9KB Ps = 25600 B (6 blocks/CU cap; grid gives 4/CU).
__global__ __launch_bounds__(256) void attn_kernel(
    const unsigned short* __restrict__ QT,  // [b,h][d=64][s=2048]
    const unsigned short* __restrict__ Kb,  // [b*s][E] row-major, pre-scaled
    unsigned short* __restrict__ Ab) {      // [b*s][E] row-major
  __shared__ __attribute__((aligned(16))) unsigned short Ks[2][64 * 64];
  __shared__ __attribute__((aligned(16))) unsigned short Ps[4][16 * 72];

  const int tid = threadIdx.x;
  const int wave = tid >> 6, lane = tid & 63;
  const int quad = lane >> 4, ln = lane & 15;
  const int h = blockIdx.y, b = blockIdx.z;
  const size_t hoff  = ((size_t)b * PS) * PE + (size_t)h * PD;
  const size_t hofft = ((size_t)(b * PH + h) * PD) * PS;
  const int srow = tid >> 3, sch = tid & 7;

  int cur = 0;
  for (int pass = 0; pass < 2; ++pass) {
    const int qc = pass ? (int)blockIdx.x : 31 - (int)blockIdx.x;
    const int qw0 = qc * 64 + wave * 16;

    // Q fragment: 16 q-rows x 64 d, B-operand layout (lane ln = q-row qw0+ln)
    bf16x8 qfr[2];
#pragma unroll
    for (int c = 0; c < 2; ++c) {
      union { unsigned short u[8]; bf16x8 v; } tmp;
#pragma unroll
      for (int j = 0; j < 8; ++j)
        tmp.u[j] = QT[hofft + (size_t)(c * 32 + quad * 8 + j) * PS + qw0 + ln];
      qfr[c] = tmp.v;
    }

    // prologue: stage K tile 0 into Ks[cur]
#pragma unroll
    for (int r = 0; r < 2; ++r) {
      const int row = r * 32 + srow;
      const int gch = sch ^ (row & 7);
      __builtin_amdgcn_global_load_lds(
          (gas_t)(const void*)(Kb + hoff + (size_t)row * PE + gch * 8),
          (las_t)(void*)((char*)&Ks[cur][0] + (r * 256 + tid) * 16), 16, 0, 0);
    }
    __syncthreads();

    f32x4 o[4];
    float psum = 0.f;
#pragma unroll
    for (int td = 0; td < 4; ++td)
#pragma unroll
      for (int r = 0; r < 4; ++r) o[td][r] = 0.f;

    const int ktend = qc + 1;
    for (int kt = 0; kt < ktend; ++kt) {
      const int k0 = kt * 64;

      // 1) issue DMA for NEXT K tile into the other buffer (prefetch)
      if (kt + 1 < ktend) {
        const int nk0 = k0 + 64;
#pragma unroll
        for (int r = 0; r < 2; ++r) {
          const int row = r * 32 + srow;
          const int gch = sch ^ (row & 7);
          __builtin_amdgcn_global_load_lds(
              (gas_t)(const void*)(Kb + hoff + (size_t)(nk0 + row) * PE + gch * 8),
              (las_t)(void*)((char*)&Ks[cur ^ 1][0] + (r * 256 + tid) * 16),
              16, 0, 0);
        }
      }

      // 2) issue V fragment loads (direct global, land under QK^T+softmax)
      bf16x8 vf[2][4];
#pragma unroll
      for (int c = 0; c < 2; ++c)
#pragma unroll
        for (int td = 0; td < 4; ++td)
          vf[c][td] = *(const bf16x8*)(QT + hofft +
              (size_t)(td * 16 + ln) * PS + k0 + (c * 4 + quad) * 8);

      // 3) QK^T from Ks[cur]: sacc[mk] covers k-rows mk*16+quad*4+r, q-col ln
      const unsigned short* kcur = &Ks[cur][0];
      f32x4 sacc[4];
#pragma unroll
      for (int mk = 0; mk < 4; ++mk)
#pragma unroll
        for (int r = 0; r < 4; ++r) sacc[mk][r] = 0.f;
      __builtin_amdgcn_s_setprio(1);
#pragma unroll
      for (int c = 0; c < 2; ++c) {
        const int ch = ((c * 4 + quad) ^ (ln & 7)) * 8;
        bf16x8 kf[4];
#pragma unroll
        for (int mk = 0; mk < 4; ++mk)
          kf[mk] = *(const bf16x8*)(kcur + (mk * 16 + ln) * 64 + ch);
#pragma unroll
        for (int mk = 0; mk < 4; ++mk)
          sacc[mk] = mfma16(kf[mk], qfr[c], sacc[mk]);
      }
      __builtin_amdgcn_s_setprio(0);

      // 4) softmax partial (K pre-scaled: exp2 directly)
      const bool edge = (k0 + 63) > qw0;
#pragma unroll
      for (int mk = 0; mk < 4; ++mk) {
        float p[4];
#pragma unroll
        for (int r = 0; r < 4; ++r)
          p[r] = __builtin_amdgcn_exp2f(sacc[mk][r]);
        if (edge) {
          const int qg = qw0 + ln;
#pragma unroll
          for (int r = 0; r < 4; ++r) {
            const int kg = k0 + mk * 16 + quad * 4 + r;
            p[r] = (kg <= qg) ? p[r] : 0.f;
          }
        }
        psum += (p[0] + p[1]) + (p[2] + p[3]);
        union { __hip_bfloat162 h2; unsigned int u; } u01, u23;
        u01.h2 = __float22bfloat162_rn(float2{p[0], p[1]});
        u23.h2 = __float22bfloat162_rn(float2{p[2], p[3]});
        *(uint2*)(&Ps[wave][ln * 72 + mk * 16 + quad * 4]) =
            uint2{u01.u, u23.u};
      }

      // 5) PV: o[td] covers d-cols td*16+ln, q-rows quad*4+r
      __builtin_amdgcn_s_setprio(1);
#pragma unroll
      for (int c = 0; c < 2; ++c) {
        bf16x8 pf = *(const bf16x8*)(&Ps[wave][ln * 72 + c * 32 + quad * 8]);
#pragma unroll
        for (int td = 0; td < 4; ++td)
          o[td] = mfma16(pf, vf[c][td], o[td]);
      }
      __builtin_amdgcn_s_setprio(0);

      // single barrier per tile: waits the prefetch DMA (issued one full
      // tile of compute ago) and closes the Ks[cur] read window.
      __syncthreads();
      cur ^= 1;
    }

    psum += __shfl_xor(psum, 16, 64);
    psum += __shfl_xor(psum, 32, 64);
    float invq[4];
#pragma unroll
    for (int r = 0; r < 4; ++r)
      invq[r] = 1.f / __shfl(psum, quad * 4 + r, 64);

#pragma unroll
    for (int r = 0; r < 4; ++r) {
      const int qg = qw0 + quad * 4 + r;
#pragma unroll
      for (int td = 0; td < 4; ++td)
        Ab[hoff + (size_t)qg * PE + td * 16 + ln] =
            f2bf(o[td][r] * invq[r]);
    }
  }
}

// ---------------------------------------------------------------------------
extern "C" void kernel_launch(void* const* d_in, const int* in_sizes, int n_in,
                              void* d_out, int out_size, void* d_ws, size_t ws_size,
                              hipStream_t stream) {
  (void)in_sizes; (void)n_in; (void)out_size; (void)ws_size;
  const float* x  = (const float*)d_in[0];
  const float* Wk = (const float*)d_in[1];
  const float* Wq = (const float*)d_in[2];
  // d_in[3] = Wv : dead in the reference (V = Q bug) — never touched.
  const float* Wo = (const float*)d_in[4];
  const float* bo = (const float*)d_in[5];
  float* out = (float*)d_out;

  char* ws = (char*)d_ws;
  unsigned short* xb  = (unsigned short*)(ws);                       // 16 MiB
  unsigned short* wkb = (unsigned short*)(ws + (16u << 20));         //  2 MiB
  unsigned short* wqb = (unsigned short*)(ws + (18u << 20));         //  2 MiB
  unsigned short* wob = (unsigned short*)(ws + (20u << 20));         //  2 MiB
  unsigned short* QT  = (unsigned short*)(ws + (22u << 20));         // 16 MiB
  unsigned short* Kb  = (unsigned short*)(ws + (38u << 20));         // 16 MiB
  unsigned short* Ab  = xb;  // alias: xb dead after gemm_qk

  const int M = PB * PS;  // 8192

  // 1) fp32 -> bf16
  cvt_kernel<<<dim3(CVT_BLOCKS), dim3(256), 0, stream>>>(
      x, Wk, Wq, Wo, xb, wkb, wqb, wob);

  // 2) fused: Q = x Wq^T (-> QT transposed), K = x Wk^T (-> row-major, scaled)
  gemm_qk<<<dim3(PE / 128, M / 128), dim3(256), 0, stream>>>(
      xb, wqb, wkb, QT, Kb);

  // 3) causal attention (V = Q) — 64-row q-chunk pairs, 2-phase pipeline
  attn_kernel<<<dim3(16, PH, PB), dim3(256), 0, stream>>>(QT, Kb, Ab);

  // 4) out = attn Wo^T + bo (fp32)
  gemm_out<<<dim3(PE / 128, M / 128), dim3(256), 0, stream>>>(
      Ab, wob, bo, out);
}

// Round 3
// 276.967 us; speedup vs baseline: 1.2806x; 1.2806x over previous
//
#include <hip/hip_runtime.h>
#include <hip/hip_bf16.h>

// Problem constants (B,S,E,H,D) = (4,2048,1024,16,64)
#define PB 4
#define PS 2048
#define PE 1024
#define PH 16
#define PD 64

typedef __attribute__((ext_vector_type(8))) short bf16x8;
typedef __attribute__((ext_vector_type(4))) float f32x4;
typedef const __attribute__((address_space(1))) unsigned int* gas_t;
typedef __attribute__((address_space(3))) unsigned int* las_t;

__device__ __forceinline__ unsigned short f2bf(float f) {
  union { float f; unsigned int u; } v;
  v.f = f;
  unsigned int u = v.u;
  u += 0x7fffu + ((u >> 16) & 1u);  // RNE
  return (unsigned short)(u >> 16);
}

__device__ __forceinline__ f32x4 mfma16(bf16x8 a, bf16x8 b, f32x4 c) {
  return __builtin_amdgcn_mfma_f32_16x16x32_bf16(a, b, c, 0, 0, 0);
}

// ---------------- fp32 -> bf16 conversion (x, Wk, Wq, Wo fused) --------------
#define CVT_GROUPS ((PB * PS * PE + 3 * PE * PE) / 4)
#define CVT_BLOCKS (CVT_GROUPS / 256)   // 11264
__global__ __launch_bounds__(256) void cvt_kernel(
    const float* __restrict__ x, const float* __restrict__ wk,
    const float* __restrict__ wq, const float* __restrict__ wo,
    unsigned short* __restrict__ xb, unsigned short* __restrict__ wkb,
    unsigned short* __restrict__ wqb, unsigned short* __restrict__ wob) {
  const long long NX = (long long)PB * PS * PE;   // 8388608
  const long long NW = (long long)PE * PE;        // 1048576
  long long i = ((long long)blockIdx.x * 256 + threadIdx.x) * 4;
  const float* src;
  unsigned short* dst;
  long long off;
  if (i < NX)               { src = x;  dst = xb;  off = i; }
  else if (i < NX + NW)     { src = wk; dst = wkb; off = i - NX; }
  else if (i < NX + 2 * NW) { src = wq; dst = wqb; off = i - NX - NW; }
  else                      { src = wo; dst = wob; off = i - NX - 2 * NW; }
  float4 v = *(const float4*)(src + off);
  ushort4 o;
  o.x = f2bf(v.x); o.y = f2bf(v.y); o.z = f2bf(v.z); o.w = f2bf(v.w);
  *(ushort4*)(dst + off) = o;
}

// ---------------- fused Q+K NT GEMM --------------------------------------
// {Q,K}[M,N] = x[M,K] * {Wq,Wk}[N,K]^T. 128x128 tile, BK=64, A-tile staged
// ONCE for both outputs. LDS layout [row][8 chunks of 8 elem] with
// GLOBAL-side XOR chunk swizzle; DMA dest stays lane-contiguous.
// Q written TRANSPOSED per-head (QT[((b*PH+h)*PD+d)*PS+s]); K row-major,
// PRE-SCALED by log2(e)/32 so attn's exp2 needs no per-score multiply
// (Q cannot be scaled: QT doubles as V via the reference's V=Q bug).
__global__ __launch_bounds__(256) void gemm_qk(
    const unsigned short* __restrict__ A, const unsigned short* __restrict__ Bq,
    const unsigned short* __restrict__ Bk,
    unsigned short* __restrict__ QT, unsigned short* __restrict__ Kb) {
  const int K = PE, N = PE;
  __shared__ __attribute__((aligned(16))) unsigned short As[128 * 64];
  __shared__ __attribute__((aligned(16))) unsigned short Bqs[128 * 64];
  __shared__ __attribute__((aligned(16))) unsigned short Bks[128 * 64];
  const int tid = threadIdx.x;
  const int wave = tid >> 6, lane = tid & 63;
  const int quad = lane >> 4, ln = lane & 15;
  const int m0 = blockIdx.y * 128, n0 = blockIdx.x * 128;
  const int wm = (wave >> 1) * 64, wn = (wave & 1) * 64;

  f32x4 aq[4][4], ak[4][4];
#pragma unroll
  for (int i = 0; i < 4; ++i)
#pragma unroll
    for (int j = 0; j < 4; ++j)
#pragma unroll
      for (int r = 0; r < 4; ++r) { aq[i][j][r] = 0.f; ak[i][j][r] = 0.f; }

  for (int k0 = 0; k0 < K; k0 += 64) {
#pragma unroll
    for (int it = 0; it < 4; ++it) {
      const int idx = it * 256 + tid;
      const int row = idx >> 3, ch = idx & 7;
      const int gch = ch ^ (row & 7);
      __builtin_amdgcn_global_load_lds(
          (gas_t)(const void*)(A + (size_t)(m0 + row) * K + k0 + gch * 8),
          (las_t)(void*)((char*)As + idx * 16), 16, 0, 0);
      __builtin_amdgcn_global_load_lds(
          (gas_t)(const void*)(Bq + (size_t)(n0 + row) * K + k0 + gch * 8),
          (las_t)(void*)((char*)Bqs + idx * 16), 16, 0, 0);
      __builtin_amdgcn_global_load_lds(
          (gas_t)(const void*)(Bk + (size_t)(n0 + row) * K + k0 + gch * 8),
          (las_t)(void*)((char*)Bks + idx * 16), 16, 0, 0);
    }
    __syncthreads();
#pragma unroll
    for (int kc = 0; kc < 2; ++kc) {
      bf16x8 af[4], bqf[4], bkf[4];
#pragma unroll
      for (int t = 0; t < 4; ++t) {
        const int ra = wm + t * 16 + ln;
        const int rb = wn + t * 16 + ln;
        af[t]  = *(const bf16x8*)(As  + ra * 64 + ((kc * 4 + quad) ^ (ra & 7)) * 8);
        bqf[t] = *(const bf16x8*)(Bqs + rb * 64 + ((kc * 4 + quad) ^ (rb & 7)) * 8);
        bkf[t] = *(const bf16x8*)(Bks + rb * 64 + ((kc * 4 + quad) ^ (rb & 7)) * 8);
      }
#pragma unroll
      for (int mt = 0; mt < 4; ++mt)
#pragma unroll
        for (int nt = 0; nt < 4; ++nt) {
          aq[mt][nt] = mfma16(af[mt], bqf[nt], aq[mt][nt]);
          ak[mt][nt] = mfma16(af[mt], bkf[nt], ak[mt][nt]);
        }
    }
    __syncthreads();
  }

  const float CEXP = 0.045084220f;  // log2(e)/32 folded into K
#pragma unroll
  for (int mt = 0; mt < 4; ++mt) {
#pragma unroll
    for (int nt = 0; nt < 4; ++nt) {
      const int row = m0 + wm + mt * 16 + quad * 4;  // +r
      const int col = n0 + wn + nt * 16 + ln;
      // Q: transposed per-head store (4 consecutive tokens -> one 8B store)
      const int b = row >> 11, s = row & 2047;
      const int h = col >> 6, d = col & 63;
      ushort4 ov;
      ov.x = f2bf(aq[mt][nt][0]); ov.y = f2bf(aq[mt][nt][1]);
      ov.z = f2bf(aq[mt][nt][2]); ov.w = f2bf(aq[mt][nt][3]);
      *(ushort4*)(QT + (((size_t)(b * PH + h) * PD + d) * PS + s)) = ov;
      // K: row-major, pre-scaled
#pragma unroll
      for (int r = 0; r < 4; ++r)
        Kb[(size_t)(row + r) * N + col] = f2bf(ak[mt][nt][r] * CEXP);
    }
  }
}

// ---------------- out-projection NT GEMM: C = A * Wo^T + bo (fp32) ----------
__global__ __launch_bounds__(256) void gemm_out(
    const unsigned short* __restrict__ A, const unsigned short* __restrict__ Bm,
    const float* __restrict__ bias, float* __restrict__ Cf) {
  const int K = PE, N = PE;
  __shared__ __attribute__((aligned(16))) unsigned short As[128 * 64];
  __shared__ __attribute__((aligned(16))) unsigned short Bs[128 * 64];
  const int tid = threadIdx.x;
  const int wave = tid >> 6, lane = tid & 63;
  const int quad = lane >> 4, ln = lane & 15;
  const int m0 = blockIdx.y * 128, n0 = blockIdx.x * 128;
  const int wm = (wave >> 1) * 64, wn = (wave & 1) * 64;

  f32x4 acc[4][4];
#pragma unroll
  for (int i = 0; i < 4; ++i)
#pragma unroll
    for (int j = 0; j < 4; ++j)
#pragma unroll
      for (int r = 0; r < 4; ++r) acc[i][j][r] = 0.f;

  for (int k0 = 0; k0 < K; k0 += 64) {
#pragma unroll
    for (int it = 0; it < 4; ++it) {
      const int idx = it * 256 + tid;
      const int row = idx >> 3, ch = idx & 7;
      const int gch = ch ^ (row & 7);
      __builtin_amdgcn_global_load_lds(
          (gas_t)(const void*)(A + (size_t)(m0 + row) * K + k0 + gch * 8),
          (las_t)(void*)((char*)As + idx * 16), 16, 0, 0);
      __builtin_amdgcn_global_load_lds(
          (gas_t)(const void*)(Bm + (size_t)(n0 + row) * K + k0 + gch * 8),
          (las_t)(void*)((char*)Bs + idx * 16), 16, 0, 0);
    }
    __syncthreads();
#pragma unroll
    for (int kc = 0; kc < 2; ++kc) {
      bf16x8 af[4], bfr[4];
#pragma unroll
      for (int t = 0; t < 4; ++t) {
        const int ra = wm + t * 16 + ln;
        const int rb = wn + t * 16 + ln;
        af[t]  = *(const bf16x8*)(As + ra * 64 + ((kc * 4 + quad) ^ (ra & 7)) * 8);
        bfr[t] = *(const bf16x8*)(Bs + rb * 64 + ((kc * 4 + quad) ^ (rb & 7)) * 8);
      }
#pragma unroll
      for (int mt = 0; mt < 4; ++mt)
#pragma unroll
        for (int nt = 0; nt < 4; ++nt)
          acc[mt][nt] = mfma16(af[mt], bfr[nt], acc[mt][nt]);
    }
    __syncthreads();
  }

#pragma unroll
  for (int mt = 0; mt < 4; ++mt) {
#pragma unroll
    for (int nt = 0; nt < 4; ++nt) {
      const int row = m0 + wm + mt * 16 + quad * 4;
      const int col = n0 + wn + nt * 16 + ln;
      const float bv = bias[col];
#pragma unroll
      for (int r = 0; r < 4; ++r)
        Cf[(size_t)(row + r) * N + col] = acc[mt][nt][r] + bv;
    }
  }
}

// ---------------- fused causal attention, V == Q (reference bug) -------------
// v4: 2-phase pipeline with ALL in-tile consumption from LDS (m97 shape).
//  * K AND V double-buffered in LDS; next tile's DMA issued at loop top,
//    tile t computed entirely from [cur] buffers, ONE barrier per tile.
//    The compiler's vmcnt(0) drain at the barrier lands a full tile of
//    compute (~400+ cyc) after DMA issue -> latency hidden.
//    (v3 failed: per-tile V global loads were younger than the K prefetch
//    in vmcnt order, so waiting for V drained the prefetch mid-tile.)
//  * s_setprio(1) around MFMA clusters (T5).
// LDS: 2*8K (Ks) + 2*8K (Vs) + 9216 (Ps) = 41984 B -> 3 blocks/CU cap.
__global__ __launch_bounds__(256) void attn_kernel(
    const unsigned short* __restrict__ QT,  // [b,h][d=64][s=2048]
    const unsigned short* __restrict__ Kb,  // [b*s][E] row-major, pre-scaled
    unsigned short* __restrict__ Ab) {      // [b*s][E] row-major
  __shared__ __attribute__((aligned(16))) unsigned short Ks[2][64 * 64];
  __shared__ __attribute__((aligned(16))) unsigned short Vs[2][64 * 64];
  __shared__ __attribute__((aligned(16))) unsigned short Ps[4][16 * 72];

  const int tid = threadIdx.x;
  const int wave = tid >> 6, lane = tid & 63;
  const int quad = lane >> 4, ln = lane & 15;
  const int h = blockIdx.y, b = blockIdx.z;
  const size_t hoff  = ((size_t)b * PS) * PE + (size_t)h * PD;
  const size_t hofft = ((size_t)(b * PH + h) * PD) * PS;
  const int srow = tid >> 3, sch = tid & 7;

  int cur = 0;
  for (int pass = 0; pass < 2; ++pass) {
    const int qc = pass ? (int)blockIdx.x : 31 - (int)blockIdx.x;
    const int qw0 = qc * 64 + wave * 16;

    // Q fragment: 16 q-rows x 64 d, B-operand layout (lane ln = q-row qw0+ln)
    bf16x8 qfr[2];
#pragma unroll
    for (int c = 0; c < 2; ++c) {
      union { unsigned short u[8]; bf16x8 v; } tmp;
#pragma unroll
      for (int j = 0; j < 8; ++j)
        tmp.u[j] = QT[hofft + (size_t)(c * 32 + quad * 8 + j) * PS + qw0 + ln];
      qfr[c] = tmp.v;
    }

    // prologue: stage tile 0 (K and V) into [cur]
#pragma unroll
    for (int r = 0; r < 2; ++r) {
      const int row = r * 32 + srow;
      const int gch = sch ^ (row & 7);
      __builtin_amdgcn_global_load_lds(
          (gas_t)(const void*)(Kb + hoff + (size_t)row * PE + gch * 8),
          (las_t)(void*)((char*)&Ks[cur][0] + (r * 256 + tid) * 16), 16, 0, 0);
      __builtin_amdgcn_global_load_lds(
          (gas_t)(const void*)(QT + hofft + (size_t)row * PS + gch * 8),
          (las_t)(void*)((char*)&Vs[cur][0] + (r * 256 + tid) * 16), 16, 0, 0);
    }
    __syncthreads();

    f32x4 o[4];
    float psum = 0.f;
#pragma unroll
    for (int td = 0; td < 4; ++td)
#pragma unroll
      for (int r = 0; r < 4; ++r) o[td][r] = 0.f;

    const int ktend = qc + 1;
    for (int kt = 0; kt < ktend; ++kt) {
      const int k0 = kt * 64;

      // 1) issue DMA for NEXT tile (K and V) into the other buffers
      if (kt + 1 < ktend) {
        const int nk0 = k0 + 64;
#pragma unroll
        for (int r = 0; r < 2; ++r) {
          const int row = r * 32 + srow;
          const int gch = sch ^ (row & 7);
          __builtin_amdgcn_global_load_lds(
              (gas_t)(const void*)(Kb + hoff + (size_t)(nk0 + row) * PE + gch * 8),
              (las_t)(void*)((char*)&Ks[cur ^ 1][0] + (r * 256 + tid) * 16),
              16, 0, 0);
          __builtin_amdgcn_global_load_lds(
              (gas_t)(const void*)(QT + hofft + (size_t)row * PS + nk0 + gch * 8),
              (las_t)(void*)((char*)&Vs[cur ^ 1][0] + (r * 256 + tid) * 16),
              16, 0, 0);
        }
      }

      // 2) QK^T from Ks[cur]: sacc[mk] covers k-rows mk*16+quad*4+r, q-col ln
      const unsigned short* kcur = &Ks[cur][0];
      const unsigned short* vcur = &Vs[cur][0];
      f32x4 sacc[4];
#pragma unroll
      for (int mk = 0; mk < 4; ++mk)
#pragma unroll
        for (int r = 0; r < 4; ++r) sacc[mk][r] = 0.f;
      __builtin_amdgcn_s_setprio(1);
#pragma unroll
      for (int c = 0; c < 2; ++c) {
        const int ch = ((c * 4 + quad) ^ (ln & 7)) * 8;
        bf16x8 kf[4];
#pragma unroll
        for (int mk = 0; mk < 4; ++mk)
          kf[mk] = *(const bf16x8*)(kcur + (mk * 16 + ln) * 64 + ch);
#pragma unroll
        for (int mk = 0; mk < 4; ++mk)
          sacc[mk] = mfma16(kf[mk], qfr[c], sacc[mk]);
      }
      __builtin_amdgcn_s_setprio(0);

      // 3) softmax partial (K pre-scaled: exp2 directly)
      const bool edge = (k0 + 63) > qw0;
#pragma unroll
      for (int mk = 0; mk < 4; ++mk) {
        float p[4];
#pragma unroll
        for (int r = 0; r < 4; ++r)
          p[r] = __builtin_amdgcn_exp2f(sacc[mk][r]);
        if (edge) {
          const int qg = qw0 + ln;
#pragma unroll
          for (int r = 0; r < 4; ++r) {
            const int kg = k0 + mk * 16 + quad * 4 + r;
            p[r] = (kg <= qg) ? p[r] : 0.f;
          }
        }
        psum += (p[0] + p[1]) + (p[2] + p[3]);
        union { __hip_bfloat162 h2; unsigned int u; } u01, u23;
        u01.h2 = __float22bfloat162_rn(float2{p[0], p[1]});
        u23.h2 = __float22bfloat162_rn(float2{p[2], p[3]});
        *(uint2*)(&Ps[wave][ln * 72 + mk * 16 + quad * 4]) =
            uint2{u01.u, u23.u};
      }

      // 4) PV from Vs[cur]: o[td] covers d-cols td*16+ln, q-rows quad*4+r
      __builtin_amdgcn_s_setprio(1);
#pragma unroll
      for (int c = 0; c < 2; ++c) {
        const int ch = ((c * 4 + quad) ^ (ln & 7)) * 8;
        bf16x8 pf = *(const bf16x8*)(&Ps[wave][ln * 72 + c * 32 + quad * 8]);
#pragma unroll
        for (int td = 0; td < 4; ++td) {
          bf16x8 vfd = *(const bf16x8*)(vcur + (td * 16 + ln) * 64 + ch);
          o[td] = mfma16(pf, vfd, o[td]);
        }
      }
      __builtin_amdgcn_s_setprio(0);

      // single barrier per tile: closes the [cur] read window; the
      // compiler's vmcnt(0) drain lands ~1 full tile after DMA issue.
      __syncthreads();
      cur ^= 1;
    }

    psum += __shfl_xor(psum, 16, 64);
    psum += __shfl_xor(psum, 32, 64);
    float invq[4];
#pragma unroll
    for (int r = 0; r < 4; ++r)
      invq[r] = 1.f / __shfl(psum, quad * 4 + r, 64);

#pragma unroll
    for (int r = 0; r < 4; ++r) {
      const int qg = qw0 + quad * 4 + r;
#pragma unroll
      for (int td = 0; td < 4; ++td)
        Ab[hoff + (size_t)qg * PE + td * 16 + ln] =
            f2bf(o[td][r] * invq[r]);
    }
  }
}

// ---------------------------------------------------------------------------
extern "C" void kernel_launch(void* const* d_in, const int* in_sizes, int n_in,
                              void* d_out, int out_size, void* d_ws, size_t ws_size,
                              hipStream_t stream) {
  (void)in_sizes; (void)n_in; (void)out_size; (void)ws_size;
  const float* x  = (const float*)d_in[0];
  const float* Wk = (const float*)d_in[1];
  const float* Wq = (const float*)d_in[2];
  // d_in[3] = Wv : dead in the reference (V = Q bug) — never touched.
  const float* Wo = (const float*)d_in[4];
  const float* bo = (const float*)d_in[5];
  float* out = (float*)d_out;

  char* ws = (char*)d_ws;
  unsigned short* xb  = (unsigned short*)(ws);                       // 16 MiB
  unsigned short* wkb = (unsigned short*)(ws + (16u << 20));         //  2 MiB
  unsigned short* wqb = (unsigned short*)(ws + (18u << 20));         //  2 MiB
  unsigned short* wob = (unsigned short*)(ws + (20u << 20));         //  2 MiB
  unsigned short* QT  = (unsigned short*)(ws + (22u << 20));         // 16 MiB
  unsigned short* Kb  = (unsigned short*)(ws + (38u << 20));         // 16 MiB
  unsigned short* Ab  = xb;  // alias: xb dead after gemm_qk

  const int M = PB * PS;  // 8192

  // 1) fp32 -> bf16
  cvt_kernel<<<dim3(CVT_BLOCKS), dim3(256), 0, stream>>>(
      x, Wk, Wq, Wo, xb, wkb, wqb, wob);

  // 2) fused: Q = x Wq^T (-> QT transposed), K = x Wk^T (-> row-major, scaled)
  gemm_qk<<<dim3(PE / 128, M / 128), dim3(256), 0, stream>>>(
      xb, wqb, wkb, QT, Kb);

  // 3) causal attention (V = Q) — 64-row q-chunk pairs, LDS-dbuf pipeline
  attn_kernel<<<dim3(16, PH, PB), dim3(256), 0, stream>>>(QT, Kb, Ab);

  // 4) out = attn Wo^T + bo (fp32)
  gemm_out<<<dim3(PE / 128, M / 128), dim3(256), 0, stream>>>(
      Ab, wob, bo, out);
}

// Round 4
// 257.308 us; speedup vs baseline: 1.3784x; 1.0764x over previous
//
#include <hip/hip_runtime.h>
#include <hip/hip_bf16.h>

// Problem constants (B,S,E,H,D) = (4,2048,1024,16,64)
#define PB 4
#define PS 2048
#define PE 1024
#define PH 16
#define PD 64

typedef __attribute__((ext_vector_type(8))) short bf16x8;
typedef __attribute__((ext_vector_type(4))) float f32x4;
typedef const __attribute__((address_space(1))) unsigned int* gas_t;
typedef __attribute__((address_space(3))) unsigned int* las_t;

__device__ __forceinline__ unsigned short f2bf(float f) {
  union { float f; unsigned int u; } v;
  v.f = f;
  unsigned int u = v.u;
  u += 0x7fffu + ((u >> 16) & 1u);  // RNE
  return (unsigned short)(u >> 16);
}

__device__ __forceinline__ f32x4 mfma16(bf16x8 a, bf16x8 b, f32x4 c) {
  return __builtin_amdgcn_mfma_f32_16x16x32_bf16(a, b, c, 0, 0, 0);
}

// ---------------- fp32 -> bf16 conversion (x, Wk, Wq, Wo fused) --------------
#define CVT_GROUPS ((PB * PS * PE + 3 * PE * PE) / 4)
#define CVT_BLOCKS (CVT_GROUPS / 256)   // 11264
__global__ __launch_bounds__(256) void cvt_kernel(
    const float* __restrict__ x, const float* __restrict__ wk,
    const float* __restrict__ wq, const float* __restrict__ wo,
    unsigned short* __restrict__ xb, unsigned short* __restrict__ wkb,
    unsigned short* __restrict__ wqb, unsigned short* __restrict__ wob) {
  const long long NX = (long long)PB * PS * PE;   // 8388608
  const long long NW = (long long)PE * PE;        // 1048576
  long long i = ((long long)blockIdx.x * 256 + threadIdx.x) * 4;
  const float* src;
  unsigned short* dst;
  long long off;
  if (i < NX)               { src = x;  dst = xb;  off = i; }
  else if (i < NX + NW)     { src = wk; dst = wkb; off = i - NX; }
  else if (i < NX + 2 * NW) { src = wq; dst = wqb; off = i - NX - NW; }
  else                      { src = wo; dst = wob; off = i - NX - 2 * NW; }
  float4 v = *(const float4*)(src + off);
  ushort4 o;
  o.x = f2bf(v.x); o.y = f2bf(v.y); o.z = f2bf(v.z); o.w = f2bf(v.w);
  *(ushort4*)(dst + off) = o;
}

// ---------------- fused Q+K NT GEMM --------------------------------------
// {Q,K}[M,N] = x[M,K] * {Wq,Wk}[N,K]^T. 128x128 tile, BK=64, A-tile staged
// ONCE for both outputs. LDS layout [row][8 chunks of 8 elem] with
// GLOBAL-side XOR chunk swizzle; DMA dest stays lane-contiguous.
// Q written TRANSPOSED per-head (QT[((b*PH+h)*PD+d)*PS+s]); K row-major,
// PRE-SCALED by log2(e)/32 so attn's exp2 needs no per-score multiply
// (Q cannot be scaled: QT doubles as V via the reference's V=Q bug).
// K accumulator uses SWAPPED MFMA operands (mfma(B,A)) so each lane holds
// 4 consecutive FEATURES for one token -> ushort4 K-stores (was 64 scalar
// 2B stores per lane-tile).
__global__ __launch_bounds__(256) void gemm_qk(
    const unsigned short* __restrict__ A, const unsigned short* __restrict__ Bq,
    const unsigned short* __restrict__ Bk,
    unsigned short* __restrict__ QT, unsigned short* __restrict__ Kb) {
  const int K = PE, N = PE;
  __shared__ __attribute__((aligned(16))) unsigned short As[128 * 64];
  __shared__ __attribute__((aligned(16))) unsigned short Bqs[128 * 64];
  __shared__ __attribute__((aligned(16))) unsigned short Bks[128 * 64];
  const int tid = threadIdx.x;
  const int wave = tid >> 6, lane = tid & 63;
  const int quad = lane >> 4, ln = lane & 15;
  const int m0 = blockIdx.y * 128, n0 = blockIdx.x * 128;
  const int wm = (wave >> 1) * 64, wn = (wave & 1) * 64;

  f32x4 aq[4][4], ak[4][4];
#pragma unroll
  for (int i = 0; i < 4; ++i)
#pragma unroll
    for (int j = 0; j < 4; ++j)
#pragma unroll
      for (int r = 0; r < 4; ++r) { aq[i][j][r] = 0.f; ak[i][j][r] = 0.f; }

  for (int k0 = 0; k0 < K; k0 += 64) {
#pragma unroll
    for (int it = 0; it < 4; ++it) {
      const int idx = it * 256 + tid;
      const int row = idx >> 3, ch = idx & 7;
      const int gch = ch ^ (row & 7);
      __builtin_amdgcn_global_load_lds(
          (gas_t)(const void*)(A + (size_t)(m0 + row) * K + k0 + gch * 8),
          (las_t)(void*)((char*)As + idx * 16), 16, 0, 0);
      __builtin_amdgcn_global_load_lds(
          (gas_t)(const void*)(Bq + (size_t)(n0 + row) * K + k0 + gch * 8),
          (las_t)(void*)((char*)Bqs + idx * 16), 16, 0, 0);
      __builtin_amdgcn_global_load_lds(
          (gas_t)(const void*)(Bk + (size_t)(n0 + row) * K + k0 + gch * 8),
          (las_t)(void*)((char*)Bks + idx * 16), 16, 0, 0);
    }
    __syncthreads();
#pragma unroll
    for (int kc = 0; kc < 2; ++kc) {
      bf16x8 af[4], bqf[4], bkf[4];
#pragma unroll
      for (int t = 0; t < 4; ++t) {
        const int ra = wm + t * 16 + ln;
        const int rb = wn + t * 16 + ln;
        af[t]  = *(const bf16x8*)(As  + ra * 64 + ((kc * 4 + quad) ^ (ra & 7)) * 8);
        bqf[t] = *(const bf16x8*)(Bqs + rb * 64 + ((kc * 4 + quad) ^ (rb & 7)) * 8);
        bkf[t] = *(const bf16x8*)(Bks + rb * 64 + ((kc * 4 + quad) ^ (rb & 7)) * 8);
      }
#pragma unroll
      for (int mt = 0; mt < 4; ++mt)
#pragma unroll
        for (int nt = 0; nt < 4; ++nt) {
          aq[mt][nt] = mfma16(af[mt], bqf[nt], aq[mt][nt]);
          // swapped operands: D[feat=quad*4+r][token=ln]
          ak[mt][nt] = mfma16(bkf[nt], af[mt], ak[mt][nt]);
        }
    }
    __syncthreads();
  }

  const float CEXP = 0.045084220f;  // log2(e)/32 folded into K
#pragma unroll
  for (int mt = 0; mt < 4; ++mt) {
#pragma unroll
    for (int nt = 0; nt < 4; ++nt) {
      // Q: D[token=quad*4+r][feat=ln] -> transposed per-head ushort4 store
      {
        const int row = m0 + wm + mt * 16 + quad * 4;  // token (+r)
        const int col = n0 + wn + nt * 16 + ln;        // feature
        const int b = row >> 11, s = row & 2047;
        const int h = col >> 6, d = col & 63;
        ushort4 ov;
        ov.x = f2bf(aq[mt][nt][0]); ov.y = f2bf(aq[mt][nt][1]);
        ov.z = f2bf(aq[mt][nt][2]); ov.w = f2bf(aq[mt][nt][3]);
        *(ushort4*)(QT + (((size_t)(b * PH + h) * PD + d) * PS + s)) = ov;
      }
      // K: D[feat=quad*4+r][token=ln] -> row-major ushort4 store, pre-scaled
      {
        const int krow = m0 + wm + mt * 16 + ln;        // token
        const int kcol = n0 + wn + nt * 16 + quad * 4;  // feature base
        ushort4 kv;
        kv.x = f2bf(ak[mt][nt][0] * CEXP); kv.y = f2bf(ak[mt][nt][1] * CEXP);
        kv.z = f2bf(ak[mt][nt][2] * CEXP); kv.w = f2bf(ak[mt][nt][3] * CEXP);
        *(ushort4*)(Kb + (size_t)krow * N + kcol) = kv;
      }
    }
  }
}

// ---------------- out-projection NT GEMM: C = A * Wo^T + bo (fp32) ----------
// Swapped MFMA operands -> lane holds 4 consecutive output features ->
// float4 stores (was 64 scalar fp32 stores per lane-tile).
__global__ __launch_bounds__(256) void gemm_out(
    const unsigned short* __restrict__ A, const unsigned short* __restrict__ Bm,
    const float* __restrict__ bias, float* __restrict__ Cf) {
  const int K = PE, N = PE;
  __shared__ __attribute__((aligned(16))) unsigned short As[128 * 64];
  __shared__ __attribute__((aligned(16))) unsigned short Bs[128 * 64];
  const int tid = threadIdx.x;
  const int wave = tid >> 6, lane = tid & 63;
  const int quad = lane >> 4, ln = lane & 15;
  const int m0 = blockIdx.y * 128, n0 = blockIdx.x * 128;
  const int wm = (wave >> 1) * 64, wn = (wave & 1) * 64;

  f32x4 acc[4][4];
#pragma unroll
  for (int i = 0; i < 4; ++i)
#pragma unroll
    for (int j = 0; j < 4; ++j)
#pragma unroll
      for (int r = 0; r < 4; ++r) acc[i][j][r] = 0.f;

  for (int k0 = 0; k0 < K; k0 += 64) {
#pragma unroll
    for (int it = 0; it < 4; ++it) {
      const int idx = it * 256 + tid;
      const int row = idx >> 3, ch = idx & 7;
      const int gch = ch ^ (row & 7);
      __builtin_amdgcn_global_load_lds(
          (gas_t)(const void*)(A + (size_t)(m0 + row) * K + k0 + gch * 8),
          (las_t)(void*)((char*)As + idx * 16), 16, 0, 0);
      __builtin_amdgcn_global_load_lds(
          (gas_t)(const void*)(Bm + (size_t)(n0 + row) * K + k0 + gch * 8),
          (las_t)(void*)((char*)Bs + idx * 16), 16, 0, 0);
    }
    __syncthreads();
#pragma unroll
    for (int kc = 0; kc < 2; ++kc) {
      bf16x8 af[4], bfr[4];
#pragma unroll
      for (int t = 0; t < 4; ++t) {
        const int ra = wm + t * 16 + ln;
        const int rb = wn + t * 16 + ln;
        af[t]  = *(const bf16x8*)(As + ra * 64 + ((kc * 4 + quad) ^ (ra & 7)) * 8);
        bfr[t] = *(const bf16x8*)(Bs + rb * 64 + ((kc * 4 + quad) ^ (rb & 7)) * 8);
      }
#pragma unroll
      for (int mt = 0; mt < 4; ++mt)
#pragma unroll
        for (int nt = 0; nt < 4; ++nt)
          acc[mt][nt] = mfma16(bfr[nt], af[mt], acc[mt][nt]);  // swapped
    }
    __syncthreads();
  }

#pragma unroll
  for (int mt = 0; mt < 4; ++mt) {
#pragma unroll
    for (int nt = 0; nt < 4; ++nt) {
      const int row  = m0 + wm + mt * 16 + ln;        // token
      const int colb = n0 + wn + nt * 16 + quad * 4;  // feature base
      const float4 bv = *(const float4*)(bias + colb);
      float4 ov;
      ov.x = acc[mt][nt][0] + bv.x; ov.y = acc[mt][nt][1] + bv.y;
      ov.z = acc[mt][nt][2] + bv.z; ov.w = acc[mt][nt][3] + bv.w;
      *(float4*)(Cf + (size_t)row * N + colb) = ov;
    }
  }
}

// ---------------- fused causal attention, V == Q (reference bug) -------------
// v5 = v2 (the 80us known-good structure: single-buffered K/V LDS staging,
// two barriers per tile, 25600B LDS -> 4 blocks/CU resident) + T5 setprio
// around the MFMA clusters. Pipelining attempts (v3: reg-V + K-prefetch;
// v4: full LDS dbuf) both LOST to cross-block overlap at this occupancy —
// reverted.
__global__ __launch_bounds__(256) void attn_kernel(
    const unsigned short* __restrict__ QT,  // [b,h][d=64][s=2048]
    const unsigned short* __restrict__ Kb,  // [b*s][E] row-major, pre-scaled
    unsigned short* __restrict__ Ab) {      // [b*s][E] row-major
  __shared__ __attribute__((aligned(16))) unsigned short Ks[64 * 64];
  __shared__ __attribute__((aligned(16))) unsigned short Vs[64 * 64];
  __shared__ __attribute__((aligned(16))) unsigned short Ps[4][16 * 72];

  const int tid = threadIdx.x;
  const int wave = tid >> 6, lane = tid & 63;
  const int quad = lane >> 4, ln = lane & 15;
  const int h = blockIdx.y, b = blockIdx.z;
  const size_t hoff  = ((size_t)b * PS) * PE + (size_t)h * PD;
  const size_t hofft = ((size_t)(b * PH + h) * PD) * PS;
  const int srow = tid >> 3, sch = tid & 7;

  for (int pass = 0; pass < 2; ++pass) {
    const int qc = pass ? (int)blockIdx.x : 31 - (int)blockIdx.x;
    const int qw0 = qc * 64 + wave * 16;

    // Q fragment: 16 q-rows x 64 d, B-operand layout (lane ln = q-row qw0+ln)
    bf16x8 qfr[2];
#pragma unroll
    for (int c = 0; c < 2; ++c) {
      union { unsigned short u[8]; bf16x8 v; } tmp;
#pragma unroll
      for (int j = 0; j < 8; ++j)
        tmp.u[j] = QT[hofft + (size_t)(c * 32 + quad * 8 + j) * PS + qw0 + ln];
      qfr[c] = tmp.v;
    }

    f32x4 o[4];
    float psum = 0.f;
#pragma unroll
    for (int td = 0; td < 4; ++td)
#pragma unroll
      for (int r = 0; r < 4; ++r) o[td][r] = 0.f;

    const int ktend = qc + 1;
    for (int kt = 0; kt < ktend; ++kt) {
      const int k0 = kt * 64;

#pragma unroll
      for (int r = 0; r < 2; ++r) {
        const int row = r * 32 + srow;
        const int gch = sch ^ (row & 7);
        __builtin_amdgcn_global_load_lds(
            (gas_t)(const void*)(Kb + hoff + (size_t)(k0 + row) * PE + gch * 8),
            (las_t)(void*)((char*)Ks + (r * 256 + tid) * 16), 16, 0, 0);
        __builtin_amdgcn_global_load_lds(
            (gas_t)(const void*)(QT + hofft + (size_t)row * PS + k0 + gch * 8),
            (las_t)(void*)((char*)Vs + (r * 256 + tid) * 16), 16, 0, 0);
      }
      __syncthreads();

      // QK^T: sacc[mk] covers k-rows (mk*16 + quad*4 + r), q-col = ln
      f32x4 sacc[4];
#pragma unroll
      for (int mk = 0; mk < 4; ++mk)
#pragma unroll
        for (int r = 0; r < 4; ++r) sacc[mk][r] = 0.f;
      __builtin_amdgcn_s_setprio(1);
#pragma unroll
      for (int c = 0; c < 2; ++c) {
        const int ch = ((c * 4 + quad) ^ (ln & 7)) * 8;
        bf16x8 kf[4];
#pragma unroll
        for (int mk = 0; mk < 4; ++mk)
          kf[mk] = *(const bf16x8*)(Ks + (mk * 16 + ln) * 64 + ch);
#pragma unroll
        for (int mk = 0; mk < 4; ++mk)
          sacc[mk] = mfma16(kf[mk], qfr[c], sacc[mk]);
      }
      __builtin_amdgcn_s_setprio(0);

      const bool edge = (k0 + 63) > qw0;
#pragma unroll
      for (int mk = 0; mk < 4; ++mk) {
        float p[4];
#pragma unroll
        for (int r = 0; r < 4; ++r)
          p[r] = __builtin_amdgcn_exp2f(sacc[mk][r]);
        if (edge) {
          const int qg = qw0 + ln;
#pragma unroll
          for (int r = 0; r < 4; ++r) {
            const int kg = k0 + mk * 16 + quad * 4 + r;
            p[r] = (kg <= qg) ? p[r] : 0.f;
          }
        }
        psum += (p[0] + p[1]) + (p[2] + p[3]);
        union { __hip_bfloat162 h2; unsigned int u; } u01, u23;
        u01.h2 = __float22bfloat162_rn(float2{p[0], p[1]});
        u23.h2 = __float22bfloat162_rn(float2{p[2], p[3]});
        *(uint2*)(&Ps[wave][ln * 72 + mk * 16 + quad * 4]) =
            uint2{u01.u, u23.u};
      }

      // PV: o[td] covers d-cols td*16+ln, q-rows quad*4+r
      __builtin_amdgcn_s_setprio(1);
#pragma unroll
      for (int c = 0; c < 2; ++c) {
        const int ch = ((c * 4 + quad) ^ (ln & 7)) * 8;
        bf16x8 pf = *(const bf16x8*)(&Ps[wave][ln * 72 + c * 32 + quad * 8]);
#pragma unroll
        for (int td = 0; td < 4; ++td) {
          bf16x8 vfd = *(const bf16x8*)(Vs + (td * 16 + ln) * 64 + ch);
          o[td] = mfma16(pf, vfd, o[td]);
        }
      }
      __builtin_amdgcn_s_setprio(0);
      __syncthreads();
    }

    psum += __shfl_xor(psum, 16, 64);
    psum += __shfl_xor(psum, 32, 64);
    float invq[4];
#pragma unroll
    for (int r = 0; r < 4; ++r)
      invq[r] = 1.f / __shfl(psum, quad * 4 + r, 64);

#pragma unroll
    for (int r = 0; r < 4; ++r) {
      const int qg = qw0 + quad * 4 + r;
#pragma unroll
      for (int td = 0; td < 4; ++td)
        Ab[hoff + (size_t)qg * PE + td * 16 + ln] =
            f2bf(o[td][r] * invq[r]);
    }
  }
}

// ---------------------------------------------------------------------------
extern "C" void kernel_launch(void* const* d_in, const int* in_sizes, int n_in,
                              void* d_out, int out_size, void* d_ws, size_t ws_size,
                              hipStream_t stream) {
  (void)in_sizes; (void)n_in; (void)out_size; (void)ws_size;
  const float* x  = (const float*)d_in[0];
  const float* Wk = (const float*)d_in[1];
  const float* Wq = (const float*)d_in[2];
  // d_in[3] = Wv : dead in the reference (V = Q bug) — never touched.
  const float* Wo = (const float*)d_in[4];
  const float* bo = (const float*)d_in[5];
  float* out = (float*)d_out;

  char* ws = (char*)d_ws;
  unsigned short* xb  = (unsigned short*)(ws);                       // 16 MiB
  unsigned short* wkb = (unsigned short*)(ws + (16u << 20));         //  2 MiB
  unsigned short* wqb = (unsigned short*)(ws + (18u << 20));         //  2 MiB
  unsigned short* wob = (unsigned short*)(ws + (20u << 20));         //  2 MiB
  unsigned short* QT  = (unsigned short*)(ws + (22u << 20));         // 16 MiB
  unsigned short* Kb  = (unsigned short*)(ws + (38u << 20));         // 16 MiB
  unsigned short* Ab  = xb;  // alias: xb dead after gemm_qk

  const int M = PB * PS;  // 8192

  // 1) fp32 -> bf16
  cvt_kernel<<<dim3(CVT_BLOCKS), dim3(256), 0, stream>>>(
      x, Wk, Wq, Wo, xb, wkb, wqb, wob);

  // 2) fused: Q = x Wq^T (-> QT transposed), K = x Wk^T (-> row-major, scaled)
  gemm_qk<<<dim3(PE / 128, M / 128), dim3(256), 0, stream>>>(
      xb, wqb, wkb, QT, Kb);

  // 3) causal attention (V = Q) — 64-row q-chunk pairs (v2 structure)
  attn_kernel<<<dim3(16, PH, PB), dim3(256), 0, stream>>>(QT, Kb, Ab);

  // 4) out = attn Wo^T + bo (fp32)
  gemm_out<<<dim3(PE / 128, M / 128), dim3(256), 0, stream>>>(
      Ab, wob, bo, out);
}

// Round 5
// 246.407 us; speedup vs baseline: 1.4394x; 1.0442x over previous
//
#include <hip/hip_runtime.h>
#include <hip/hip_bf16.h>

// Problem constants (B,S,E,H,D) = (4,2048,1024,16,64)
#define PB 4
#define PS 2048
#define PE 1024
#define PH 16
#define PD 64

typedef __attribute__((ext_vector_type(8))) short bf16x8;
typedef __attribute__((ext_vector_type(4))) float f32x4;
typedef const __attribute__((address_space(1))) unsigned int* gas_t;
typedef __attribute__((address_space(3))) unsigned int* las_t;

__device__ __forceinline__ unsigned short f2bf(float f) {
  union { float f; unsigned int u; } v;
  v.f = f;
  unsigned int u = v.u;
  u += 0x7fffu + ((u >> 16) & 1u);  // RNE
  return (unsigned short)(u >> 16);
}

__device__ __forceinline__ f32x4 mfma16(bf16x8 a, bf16x8 b, f32x4 c) {
  return __builtin_amdgcn_mfma_f32_16x16x32_bf16(a, b, c, 0, 0, 0);
}

// ---------------- fp32 -> bf16 conversion (x, Wk, Wq, Wo fused) --------------
#define CVT_GROUPS ((PB * PS * PE + 3 * PE * PE) / 4)
#define CVT_BLOCKS (CVT_GROUPS / 256)   // 11264
__global__ __launch_bounds__(256) void cvt_kernel(
    const float* __restrict__ x, const float* __restrict__ wk,
    const float* __restrict__ wq, const float* __restrict__ wo,
    unsigned short* __restrict__ xb, unsigned short* __restrict__ wkb,
    unsigned short* __restrict__ wqb, unsigned short* __restrict__ wob) {
  const long long NX = (long long)PB * PS * PE;   // 8388608
  const long long NW = (long long)PE * PE;        // 1048576
  long long i = ((long long)blockIdx.x * 256 + threadIdx.x) * 4;
  const float* src;
  unsigned short* dst;
  long long off;
  if (i < NX)               { src = x;  dst = xb;  off = i; }
  else if (i < NX + NW)     { src = wk; dst = wkb; off = i - NX; }
  else if (i < NX + 2 * NW) { src = wq; dst = wqb; off = i - NX - NW; }
  else                      { src = wo; dst = wob; off = i - NX - 2 * NW; }
  float4 v = *(const float4*)(src + off);
  ushort4 o;
  o.x = f2bf(v.x); o.y = f2bf(v.y); o.z = f2bf(v.z); o.w = f2bf(v.w);
  *(ushort4*)(dst + off) = o;
}

// ---------------- Q / K NT GEMM, split by blockIdx.z -----------------------
// C[M,N] = x[M,K] * W[N,K]^T. 128x128 tile, BK=64, blockIdx.z selects the
// output: z=0 -> Q (normal operand order; D[token][feat]; transposed
// per-head ushort4 QT store), z=1 -> K (SWAPPED operands; D[feat][token];
// row-major ushort4 store, PRE-SCALED by log2(e)/32 so attn's exp2 needs
// no per-score multiply; Q can't be scaled since QT doubles as V).
// Split rationale (R4 counters): fused 2-output version was grid-capped at
// 2 blocks/CU -> Occupancy 10%, MfmaUtil 15%, pure latency-bound. Split
// gives 1024 blocks = 4/CU, 32KB LDS (cap 5), half the accumulators.
__global__ __launch_bounds__(256) void gemm_qknt(
    const unsigned short* __restrict__ A, const unsigned short* __restrict__ Bq,
    const unsigned short* __restrict__ Bk,
    unsigned short* __restrict__ QT, unsigned short* __restrict__ Kb) {
  const int K = PE, N = PE;
  __shared__ __attribute__((aligned(16))) unsigned short As[128 * 64];
  __shared__ __attribute__((aligned(16))) unsigned short Bs[128 * 64];
  const int tid = threadIdx.x;
  const int wave = tid >> 6, lane = tid & 63;
  const int quad = lane >> 4, ln = lane & 15;
  const int m0 = blockIdx.y * 128, n0 = blockIdx.x * 128;
  const int wm = (wave >> 1) * 64, wn = (wave & 1) * 64;
  const int isK = blockIdx.z;
  const unsigned short* __restrict__ Bsrc = isK ? Bk : Bq;

  f32x4 acc[4][4];
#pragma unroll
  for (int i = 0; i < 4; ++i)
#pragma unroll
    for (int j = 0; j < 4; ++j)
#pragma unroll
      for (int r = 0; r < 4; ++r) acc[i][j][r] = 0.f;

  for (int k0 = 0; k0 < K; k0 += 64) {
#pragma unroll
    for (int it = 0; it < 4; ++it) {
      const int idx = it * 256 + tid;
      const int row = idx >> 3, ch = idx & 7;
      const int gch = ch ^ (row & 7);
      __builtin_amdgcn_global_load_lds(
          (gas_t)(const void*)(A + (size_t)(m0 + row) * K + k0 + gch * 8),
          (las_t)(void*)((char*)As + idx * 16), 16, 0, 0);
      __builtin_amdgcn_global_load_lds(
          (gas_t)(const void*)(Bsrc + (size_t)(n0 + row) * K + k0 + gch * 8),
          (las_t)(void*)((char*)Bs + idx * 16), 16, 0, 0);
    }
    __syncthreads();
#pragma unroll
    for (int kc = 0; kc < 2; ++kc) {
      bf16x8 af[4], bfr[4];
#pragma unroll
      for (int t = 0; t < 4; ++t) {
        const int ra = wm + t * 16 + ln;
        const int rb = wn + t * 16 + ln;
        af[t]  = *(const bf16x8*)(As + ra * 64 + ((kc * 4 + quad) ^ (ra & 7)) * 8);
        bfr[t] = *(const bf16x8*)(Bs + rb * 64 + ((kc * 4 + quad) ^ (rb & 7)) * 8);
      }
      if (!isK) {
#pragma unroll
        for (int mt = 0; mt < 4; ++mt)
#pragma unroll
          for (int nt = 0; nt < 4; ++nt)
            acc[mt][nt] = mfma16(af[mt], bfr[nt], acc[mt][nt]);
      } else {
#pragma unroll
        for (int mt = 0; mt < 4; ++mt)
#pragma unroll
          for (int nt = 0; nt < 4; ++nt)
            acc[mt][nt] = mfma16(bfr[nt], af[mt], acc[mt][nt]);  // swapped
      }
    }
    __syncthreads();
  }

  const float CEXP = 0.045084220f;  // log2(e)/32 folded into K
  if (!isK) {
    // Q: D[token=quad*4+r][feat=ln] -> transposed per-head ushort4 store
#pragma unroll
    for (int mt = 0; mt < 4; ++mt)
#pragma unroll
      for (int nt = 0; nt < 4; ++nt) {
        const int row = m0 + wm + mt * 16 + quad * 4;  // token (+r)
        const int col = n0 + wn + nt * 16 + ln;        // feature
        const int b = row >> 11, s = row & 2047;
        const int h = col >> 6, d = col & 63;
        ushort4 ov;
        ov.x = f2bf(acc[mt][nt][0]); ov.y = f2bf(acc[mt][nt][1]);
        ov.z = f2bf(acc[mt][nt][2]); ov.w = f2bf(acc[mt][nt][3]);
        *(ushort4*)(QT + (((size_t)(b * PH + h) * PD + d) * PS + s)) = ov;
      }
  } else {
    // K: D[feat=quad*4+r][token=ln] -> row-major ushort4 store, pre-scaled
#pragma unroll
    for (int mt = 0; mt < 4; ++mt)
#pragma unroll
      for (int nt = 0; nt < 4; ++nt) {
        const int krow = m0 + wm + mt * 16 + ln;        // token
        const int kcol = n0 + wn + nt * 16 + quad * 4;  // feature base
        ushort4 kv;
        kv.x = f2bf(acc[mt][nt][0] * CEXP); kv.y = f2bf(acc[mt][nt][1] * CEXP);
        kv.z = f2bf(acc[mt][nt][2] * CEXP); kv.w = f2bf(acc[mt][nt][3] * CEXP);
        *(ushort4*)(Kb + (size_t)krow * N + kcol) = kv;
      }
  }
}

// ---------------- out-projection NT GEMM: C = A * Wo^T + bo (fp32) ----------
// 64x128 tile (M-split) -> grid 1024 = 4 blocks/CU (was 512 = 2/CU,
// latency-bound). 24KB LDS (cap 6/CU). Wave grid 2x2, wave-tile 32x64.
// Swapped MFMA operands -> lane holds 4 consecutive output features ->
// float4 stores.
__global__ __launch_bounds__(256) void gemm_out(
    const unsigned short* __restrict__ A, const unsigned short* __restrict__ Bm,
    const float* __restrict__ bias, float* __restrict__ Cf) {
  const int K = PE, N = PE;
  __shared__ __attribute__((aligned(16))) unsigned short As[64 * 64];
  __shared__ __attribute__((aligned(16))) unsigned short Bs[128 * 64];
  const int tid = threadIdx.x;
  const int wave = tid >> 6, lane = tid & 63;
  const int quad = lane >> 4, ln = lane & 15;
  const int m0 = blockIdx.y * 64, n0 = blockIdx.x * 128;
  const int wm = (wave >> 1) * 32, wn = (wave & 1) * 64;

  f32x4 acc[2][4];
#pragma unroll
  for (int i = 0; i < 2; ++i)
#pragma unroll
    for (int j = 0; j < 4; ++j)
#pragma unroll
      for (int r = 0; r < 4; ++r) acc[i][j][r] = 0.f;

  for (int k0 = 0; k0 < K; k0 += 64) {
#pragma unroll
    for (int it = 0; it < 2; ++it) {
      const int idx = it * 256 + tid;
      const int row = idx >> 3, ch = idx & 7;
      const int gch = ch ^ (row & 7);
      __builtin_amdgcn_global_load_lds(
          (gas_t)(const void*)(A + (size_t)(m0 + row) * K + k0 + gch * 8),
          (las_t)(void*)((char*)As + idx * 16), 16, 0, 0);
    }
#pragma unroll
    for (int it = 0; it < 4; ++it) {
      const int idx = it * 256 + tid;
      const int row = idx >> 3, ch = idx & 7;
      const int gch = ch ^ (row & 7);
      __builtin_amdgcn_global_load_lds(
          (gas_t)(const void*)(Bm + (size_t)(n0 + row) * K + k0 + gch * 8),
          (las_t)(void*)((char*)Bs + idx * 16), 16, 0, 0);
    }
    __syncthreads();
#pragma unroll
    for (int kc = 0; kc < 2; ++kc) {
      bf16x8 af[2], bfr[4];
#pragma unroll
      for (int t = 0; t < 2; ++t) {
        const int ra = wm + t * 16 + ln;
        af[t] = *(const bf16x8*)(As + ra * 64 + ((kc * 4 + quad) ^ (ra & 7)) * 8);
      }
#pragma unroll
      for (int t = 0; t < 4; ++t) {
        const int rb = wn + t * 16 + ln;
        bfr[t] = *(const bf16x8*)(Bs + rb * 64 + ((kc * 4 + quad) ^ (rb & 7)) * 8);
      }
#pragma unroll
      for (int mt = 0; mt < 2; ++mt)
#pragma unroll
        for (int nt = 0; nt < 4; ++nt)
          acc[mt][nt] = mfma16(bfr[nt], af[mt], acc[mt][nt]);  // swapped
    }
    __syncthreads();
  }

#pragma unroll
  for (int mt = 0; mt < 2; ++mt) {
#pragma unroll
    for (int nt = 0; nt < 4; ++nt) {
      const int row  = m0 + wm + mt * 16 + ln;        // token
      const int colb = n0 + wn + nt * 16 + quad * 4;  // feature base
      const float4 bv = *(const float4*)(bias + colb);
      float4 ov;
      ov.x = acc[mt][nt][0] + bv.x; ov.y = acc[mt][nt][1] + bv.y;
      ov.z = acc[mt][nt][2] + bv.z; ov.w = acc[mt][nt][3] + bv.w;
      *(float4*)(Cf + (size_t)row * N + colb) = ov;
    }
  }
}

// ---------------- fused causal attention, V == Q (reference bug) -------------
// v2 structure (80us known-good: single-buffered K/V LDS staging, two
// barriers per tile, 25600B LDS -> 4 blocks/CU) + T5 setprio. Pipelining
// attempts (v3/v4) both lost to cross-block overlap — do not revisit.
__global__ __launch_bounds__(256) void attn_kernel(
    const unsigned short* __restrict__ QT,  // [b,h][d=64][s=2048]
    const unsigned short* __restrict__ Kb,  // [b*s][E] row-major, pre-scaled
    unsigned short* __restrict__ Ab) {      // [b*s][E] row-major
  __shared__ __attribute__((aligned(16))) unsigned short Ks[64 * 64];
  __shared__ __attribute__((aligned(16))) unsigned short Vs[64 * 64];
  __shared__ __attribute__((aligned(16))) unsigned short Ps[4][16 * 72];

  const int tid = threadIdx.x;
  const int wave = tid >> 6, lane = tid & 63;
  const int quad = lane >> 4, ln = lane & 15;
  const int h = blockIdx.y, b = blockIdx.z;
  const size_t hoff  = ((size_t)b * PS) * PE + (size_t)h * PD;
  const size_t hofft = ((size_t)(b * PH + h) * PD) * PS;
  const int srow = tid >> 3, sch = tid & 7;

  for (int pass = 0; pass < 2; ++pass) {
    const int qc = pass ? (int)blockIdx.x : 31 - (int)blockIdx.x;
    const int qw0 = qc * 64 + wave * 16;

    // Q fragment: 16 q-rows x 64 d, B-operand layout (lane ln = q-row qw0+ln)
    bf16x8 qfr[2];
#pragma unroll
    for (int c = 0; c < 2; ++c) {
      union { unsigned short u[8]; bf16x8 v; } tmp;
#pragma unroll
      for (int j = 0; j < 8; ++j)
        tmp.u[j] = QT[hofft + (size_t)(c * 32 + quad * 8 + j) * PS + qw0 + ln];
      qfr[c] = tmp.v;
    }

    f32x4 o[4];
    float psum = 0.f;
#pragma unroll
    for (int td = 0; td < 4; ++td)
#pragma unroll
      for (int r = 0; r < 4; ++r) o[td][r] = 0.f;

    const int ktend = qc + 1;
    for (int kt = 0; kt < ktend; ++kt) {
      const int k0 = kt * 64;

#pragma unroll
      for (int r = 0; r < 2; ++r) {
        const int row = r * 32 + srow;
        const int gch = sch ^ (row & 7);
        __builtin_amdgcn_global_load_lds(
            (gas_t)(const void*)(Kb + hoff + (size_t)(k0 + row) * PE + gch * 8),
            (las_t)(void*)((char*)Ks + (r * 256 + tid) * 16), 16, 0, 0);
        __builtin_amdgcn_global_load_lds(
            (gas_t)(const void*)(QT + hofft + (size_t)row * PS + k0 + gch * 8),
            (las_t)(void*)((char*)Vs + (r * 256 + tid) * 16), 16, 0, 0);
      }
      __syncthreads();

      // QK^T: sacc[mk] covers k-rows (mk*16 + quad*4 + r), q-col = ln
      f32x4 sacc[4];
#pragma unroll
      for (int mk = 0; mk < 4; ++mk)
#pragma unroll
        for (int r = 0; r < 4; ++r) sacc[mk][r] = 0.f;
      __builtin_amdgcn_s_setprio(1);
#pragma unroll
      for (int c = 0; c < 2; ++c) {
        const int ch = ((c * 4 + quad) ^ (ln & 7)) * 8;
        bf16x8 kf[4];
#pragma unroll
        for (int mk = 0; mk < 4; ++mk)
          kf[mk] = *(const bf16x8*)(Ks + (mk * 16 + ln) * 64 + ch);
#pragma unroll
        for (int mk = 0; mk < 4; ++mk)
          sacc[mk] = mfma16(kf[mk], qfr[c], sacc[mk]);
      }
      __builtin_amdgcn_s_setprio(0);

      const bool edge = (k0 + 63) > qw0;
#pragma unroll
      for (int mk = 0; mk < 4; ++mk) {
        float p[4];
#pragma unroll
        for (int r = 0; r < 4; ++r)
          p[r] = __builtin_amdgcn_exp2f(sacc[mk][r]);
        if (edge) {
          const int qg = qw0 + ln;
#pragma unroll
          for (int r = 0; r < 4; ++r) {
            const int kg = k0 + mk * 16 + quad * 4 + r;
            p[r] = (kg <= qg) ? p[r] : 0.f;
          }
        }
        psum += (p[0] + p[1]) + (p[2] + p[3]);
        union { __hip_bfloat162 h2; unsigned int u; } u01, u23;
        u01.h2 = __float22bfloat162_rn(float2{p[0], p[1]});
        u23.h2 = __float22bfloat162_rn(float2{p[2], p[3]});
        *(uint2*)(&Ps[wave][ln * 72 + mk * 16 + quad * 4]) =
            uint2{u01.u, u23.u};
      }

      // PV: o[td] covers d-cols td*16+ln, q-rows quad*4+r
      __builtin_amdgcn_s_setprio(1);
#pragma unroll
      for (int c = 0; c < 2; ++c) {
        const int ch = ((c * 4 + quad) ^ (ln & 7)) * 8;
        bf16x8 pf = *(const bf16x8*)(&Ps[wave][ln * 72 + c * 32 + quad * 8]);
#pragma unroll
        for (int td = 0; td < 4; ++td) {
          bf16x8 vfd = *(const bf16x8*)(Vs + (td * 16 + ln) * 64 + ch);
          o[td] = mfma16(pf, vfd, o[td]);
        }
      }
      __builtin_amdgcn_s_setprio(0);
      __syncthreads();
    }

    psum += __shfl_xor(psum, 16, 64);
    psum += __shfl_xor(psum, 32, 64);
    float invq[4];
#pragma unroll
    for (int r = 0; r < 4; ++r)
      invq[r] = 1.f / __shfl(psum, quad * 4 + r, 64);

#pragma unroll
    for (int r = 0; r < 4; ++r) {
      const int qg = qw0 + quad * 4 + r;
#pragma unroll
      for (int td = 0; td < 4; ++td)
        Ab[hoff + (size_t)qg * PE + td * 16 + ln] =
            f2bf(o[td][r] * invq[r]);
    }
  }
}

// ---------------------------------------------------------------------------
extern "C" void kernel_launch(void* const* d_in, const int* in_sizes, int n_in,
                              void* d_out, int out_size, void* d_ws, size_t ws_size,
                              hipStream_t stream) {
  (void)in_sizes; (void)n_in; (void)out_size; (void)ws_size;
  const float* x  = (const float*)d_in[0];
  const float* Wk = (const float*)d_in[1];
  const float* Wq = (const float*)d_in[2];
  // d_in[3] = Wv : dead in the reference (V = Q bug) — never touched.
  const float* Wo = (const float*)d_in[4];
  const float* bo = (const float*)d_in[5];
  float* out = (float*)d_out;

  char* ws = (char*)d_ws;
  unsigned short* xb  = (unsigned short*)(ws);                       // 16 MiB
  unsigned short* wkb = (unsigned short*)(ws + (16u << 20));         //  2 MiB
  unsigned short* wqb = (unsigned short*)(ws + (18u << 20));         //  2 MiB
  unsigned short* wob = (unsigned short*)(ws + (20u << 20));         //  2 MiB
  unsigned short* QT  = (unsigned short*)(ws + (22u << 20));         // 16 MiB
  unsigned short* Kb  = (unsigned short*)(ws + (38u << 20));         // 16 MiB
  unsigned short* Ab  = xb;  // alias: xb dead after gemm_qknt

  const int M = PB * PS;  // 8192

  // 1) fp32 -> bf16
  cvt_kernel<<<dim3(CVT_BLOCKS), dim3(256), 0, stream>>>(
      x, Wk, Wq, Wo, xb, wkb, wqb, wob);

  // 2) Q = x Wq^T (z=0, -> QT transposed), K = x Wk^T (z=1, -> row-major,
  //    scaled). 1024 blocks = 4/CU.
  gemm_qknt<<<dim3(PE / 128, M / 128, 2), dim3(256), 0, stream>>>(
      xb, wqb, wkb, QT, Kb);

  // 3) causal attention (V = Q) — 64-row q-chunk pairs (v2 structure)
  attn_kernel<<<dim3(16, PH, PB), dim3(256), 0, stream>>>(QT, Kb, Ab);

  // 4) out = attn Wo^T + bo (fp32) — 64x128 tiles, 1024 blocks = 4/CU
  gemm_out<<<dim3(PE / 128, M / 64), dim3(256), 0, stream>>>(
      Ab, wob, bo, out);
}